// Round 6
// baseline (258.436 us; speedup 1.0000x reference)
//
#include <hip/hip_runtime.h>
#include <hip/hip_fp16.h>

// MHA with softmax over HEADS axis. R6: software-pipelined LDS-DMA staging.
// attn_ctx / attn_denom: raw s_barrier + manual vmcnt(0), period t+1's DMA
// issued right after the barrier, BEFORE compute t -> loads fly during compute.
// IDn moved from LDS staging (wave-private rows = no sharing) to register
// double-buffered prefetch. Pl padded to stride 40 (2-way conflicts only).

typedef _Float16 f16;
typedef _Float16 f16x4 __attribute__((ext_vector_type(4)));
typedef _Float16 f16x8 __attribute__((ext_vector_type(8)));
typedef float    f32x4 __attribute__((ext_vector_type(4)));

#define S_LEN 2048
#define DIM   1024
#define NH    16
#define DK    64
#define SCALE 0.125f

#define MFMA(a, b, c) __builtin_amdgcn_mfma_f32_16x16x32_f16(a, b, c, 0, 0, 0)

// raw wait/barrier: no compiler-inserted full drain (cross-wave LDS data is
// exclusively DMA-written -> own-wave vmcnt + barrier is sufficient)
#define VM_WAIT0   asm volatile("s_waitcnt vmcnt(0)" ::: "memory")
#define WG_BARRIER asm volatile("s_barrier" ::: "memory")

typedef __attribute__((address_space(1))) void g_void;
typedef __attribute__((address_space(3))) void l_void;

static __device__ __forceinline__ void gload_lds16(const void* g, void* l) {
  // async global->LDS DMA; dst = wave-uniform base + lane*16 (1KB/inst)
  __builtin_amdgcn_global_load_lds((g_void*)g, (l_void*)l, 16, 0, 0);
}

// ---------------------------------------------------------------- merged cvt fp32->f16
__global__ __launch_bounds__(256) void cvt_all(
    const float* __restrict__ q, const float* __restrict__ k, const float* __restrict__ v,
    const float* __restrict__ Wq, const float* __restrict__ Wk, const float* __restrict__ Wv,
    const float* __restrict__ Wo, f16* __restrict__ qh, f16* __restrict__ kh,
    f16* __restrict__ vh, f16* __restrict__ wqh, f16* __restrict__ wkh,
    f16* __restrict__ wvh, f16* __restrict__ woh) {
  const size_t M = 1048576;
  const int seg = blockIdx.y;
  const float* src;
  f16* dst;
  switch (seg) {
    case 0: src = q;      dst = qh;      break;
    case 1: src = q + M;  dst = qh + M;  break;
    case 2: src = k;      dst = kh;      break;
    case 3: src = k + M;  dst = kh + M;  break;
    case 4: src = v;      dst = vh;      break;
    case 5: src = v + M;  dst = vh + M;  break;
    case 6: src = Wq;     dst = wqh;     break;
    case 7: src = Wk;     dst = wkh;     break;
    case 8: src = Wv;     dst = wvh;     break;
    default: src = Wo;    dst = woh;     break;
  }
  int i = blockIdx.x * 256 + threadIdx.x;
  float4 vv = ((const float4*)src)[i];
  f16x4 o = {(f16)vv.x, (f16)vv.y, (f16)vv.z, (f16)vv.w};
  ((f16x4*)dst)[i] = o;
}

__global__ __launch_bounds__(256) void cvt_f32_f16(const float* __restrict__ src,
                                                   f16* __restrict__ dst, int n4) {
  int i = blockIdx.x * 256 + threadIdx.x;
  if (i < n4) {
    float4 v = ((const float4*)src)[i];
    f16x4 o = {(f16)v.x, (f16)v.y, (f16)v.z, (f16)v.w};
    ((f16x4*)dst)[i] = o;
  }
}

// ---------------------------------------------------------------- 128x64 GEMM core, BK=64
static __device__ __forceinline__ void gemm64_core(const f16* __restrict__ X,
                                                   const f16* __restrict__ W,
                                                   int k0, int k1, int bm, int bn,
                                                   f16* As2, f16* Bs2,
                                                   f32x4 (&acc)[4][2]) {
  const int tid = threadIdx.x;
  const int wv = tid >> 6;
  const int lane = tid & 63;
  const int qd = lane >> 4;
  const int l16 = lane & 15;
  const int wm = (wv & 1) * 64;
  const int wn = (wv >> 1) * 32;
  const int lr4 = lane >> 2, lc4 = lane & 3;
  const int kkw = wv & 1;
  const int rgw = wv >> 1;

  const f16* gA = X + (size_t)(bm + rgw * 64 + lr4) * DIM + k0 + kkw * 32 + lc4 * 8;
  const f16* gB = W + (size_t)(bn + rgw * 32 + lr4) * DIM + k0 + kkw * 32 + lc4 * 8;
  f16* lA = As2 + kkw * (128 * 32) + (rgw * 64) * 32;
  f16* lB = Bs2 + kkw * (64 * 32) + (rgw * 32) * 32;

  for (int kt = k0; kt < k1; kt += 64) {
#pragma unroll
    for (int t = 0; t < 4; t++)
      gload_lds16(gA + t * 16 * DIM, lA + t * 16 * 32);
#pragma unroll
    for (int t = 0; t < 2; t++)
      gload_lds16(gB + t * 16 * DIM, lB + t * 16 * 32);
    gA += 64;
    gB += 64;
    __syncthreads();

    f16x8 af[4][2], bf[2][2];
#pragma unroll
    for (int mi = 0; mi < 4; mi++)
#pragma unroll
      for (int kk = 0; kk < 2; kk++)
        af[mi][kk] = *(const f16x8*)&As2[kk * (128 * 32) + (wm + mi * 16 + l16) * 32 + qd * 8];
#pragma unroll
    for (int ni = 0; ni < 2; ni++)
#pragma unroll
      for (int kk = 0; kk < 2; kk++)
        bf[ni][kk] = *(const f16x8*)&Bs2[kk * (64 * 32) + (wn + ni * 16 + l16) * 32 + qd * 8];
#pragma unroll
    for (int mi = 0; mi < 4; mi++)
#pragma unroll
      for (int ni = 0; ni < 2; ni++) {
        acc[mi][ni] = MFMA(af[mi][0], bf[ni][0], acc[mi][ni]);
        acc[mi][ni] = MFMA(af[mi][1], bf[ni][1], acc[mi][ni]);
      }
    __syncthreads();
  }
}

// ---------------------------------------------------------------- merged QKV proj
__global__ __launch_bounds__(256) void gemm_qkv(
    const f16* __restrict__ X0, const f16* __restrict__ X1, const f16* __restrict__ X2,
    const f16* __restrict__ W0, const f16* __restrict__ W1, const f16* __restrict__ W2,
    const float* __restrict__ b0, const float* __restrict__ b1, const float* __restrict__ b2,
    f16* __restrict__ o0, f16* __restrict__ o1, f16* __restrict__ o2) {
  __shared__ __align__(16) f16 As2[2 * 128 * 32];
  __shared__ __align__(16) f16 Bs2[2 * 64 * 32];
  const int z = blockIdx.z;
  const f16* X = z == 0 ? X0 : z == 1 ? X1 : X2;
  const f16* W = z == 0 ? W0 : z == 1 ? W1 : W2;
  const float* bias = z == 0 ? b0 : z == 1 ? b1 : b2;
  f16* outh = z == 0 ? o0 : z == 1 ? o1 : o2;

  const int bm = blockIdx.y * 128, bn = blockIdx.x * 64;
  f32x4 acc[4][2];
#pragma unroll
  for (int a = 0; a < 4; a++)
#pragma unroll
    for (int b = 0; b < 2; b++) acc[a][b] = (f32x4){0.f, 0.f, 0.f, 0.f};

  gemm64_core(X, W, 0, DIM, bm, bn, As2, Bs2, acc);

  const int tid = threadIdx.x;
  const int wv = tid >> 6, lane = tid & 63;
  const int qd = lane >> 4, l16 = lane & 15;
  const int wm = (wv & 1) * 64, wn = (wv >> 1) * 32;
#pragma unroll
  for (int mi = 0; mi < 4; mi++) {
#pragma unroll
    for (int ni = 0; ni < 2; ni++) {
      const int gm = bm + wm + mi * 16 + qd * 4;
      const int gn = bn + wn + ni * 16 + l16;
      const float bs = bias[gn];
      if (z == 2) {
        f16x4 o = {(f16)(acc[mi][ni][0] + bs), (f16)(acc[mi][ni][1] + bs),
                   (f16)(acc[mi][ni][2] + bs), (f16)(acc[mi][ni][3] + bs)};
        *(f16x4*)&outh[(size_t)gn * S_LEN + gm] = o;  // Vt[d][j]
      } else {
#pragma unroll
        for (int r = 0; r < 4; r++)
          outh[(size_t)(gm + r) * DIM + gn] = (f16)(acc[mi][ni][r] + bs);
      }
    }
  }
}

// ---------------------------------------------------------------- out GEMM 128x64, splitK2
__global__ __launch_bounds__(256) void gemm_out(const f16* __restrict__ X,
                                                const f16* __restrict__ W,
                                                const float* __restrict__ bias,
                                                float* __restrict__ outf) {
  __shared__ __align__(16) f16 As2[2 * 128 * 32];
  __shared__ __align__(16) f16 Bs2[2 * 64 * 32];
  const int z = blockIdx.z;
  const int bm = blockIdx.y * 128, bn = blockIdx.x * 64;
  f32x4 acc[4][2];
#pragma unroll
  for (int a = 0; a < 4; a++)
#pragma unroll
    for (int b = 0; b < 2; b++) acc[a][b] = (f32x4){0.f, 0.f, 0.f, 0.f};

  gemm64_core(X, W, z * (DIM / 2), (z + 1) * (DIM / 2), bm, bn, As2, Bs2, acc);

  const int tid = threadIdx.x;
  const int wv = tid >> 6, lane = tid & 63;
  const int qd = lane >> 4, l16 = lane & 15;
  const int wm = (wv & 1) * 64, wn = (wv >> 1) * 32;
#pragma unroll
  for (int mi = 0; mi < 4; mi++) {
#pragma unroll
    for (int ni = 0; ni < 2; ni++) {
      const int gm = bm + wm + mi * 16 + qd * 4;
      const int gn = bn + wn + ni * 16 + l16;
      const float bs = z == 0 ? bias[gn] : 0.f;
#pragma unroll
      for (int r = 0; r < 4; r++)
        atomicAdd(&outf[(size_t)(gm + r) * DIM + gn], acc[mi][ni][r] + bs);
    }
  }
}

// ---------------------------------------------------------------- pass A: IDn = 1/sum_h exp
// 64x64 tile, grid (S/64,S/64)=1024. Per-head Q/K slices double-buffered in LDS
// (32KB); pipelined: head h+1's DMA issued before compute h. 16 unrolled periods.
__global__ __launch_bounds__(256) void attn_denom(const f16* __restrict__ Qp,
                                                  const f16* __restrict__ Kp,
                                                  f16* __restrict__ IDn) {
  __shared__ __align__(16) f16 Qs[2][2][64 * 32];  // [buf][kk][row][32]
  __shared__ __align__(16) f16 Ks[2][2][64 * 32];
  const int tid = threadIdx.x;
  const int wv = tid >> 6;
  const int lane = tid & 63;
  const int qd = lane >> 4;
  const int l16 = lane & 15;
  const int wm = (wv & 1) * 32, wn = (wv >> 1) * 32;
  const int bi = blockIdx.y * 64, bj = blockIdx.x * 64;
  const int lr4 = lane >> 2, lc4 = lane & 3;
  const int kkw = wv & 1;          // staging: wave's kk slice
  const int q0 = (wv >> 1) * 2;    // staging: wave's row-quarter pair

  f32x4 dsum[2][2];
#pragma unroll
  for (int a = 0; a < 2; a++)
#pragma unroll
    for (int b = 0; b < 2; b++) dsum[a][b] = (f32x4){0.f, 0.f, 0.f, 0.f};

  // prologue: stage head 0 into buf 0
  {
    const f16* gq = Qp + (size_t)(bi + q0 * 16 + lr4) * DIM + 0 * DK + kkw * 32 + lc4 * 8;
    const f16* gk = Kp + (size_t)(bj + q0 * 16 + lr4) * DIM + 0 * DK + kkw * 32 + lc4 * 8;
#pragma unroll
    for (int t = 0; t < 2; t++) {
      gload_lds16(gq + (size_t)t * 16 * DIM, &Qs[0][kkw][(q0 + t) * 16 * 32]);
      gload_lds16(gk + (size_t)t * 16 * DIM, &Ks[0][kkw][(q0 + t) * 16 * 32]);
    }
  }

#pragma unroll
  for (int h = 0; h < NH; h++) {
    const int buf = h & 1;
    VM_WAIT0;     // own DMA for head h complete
    WG_BARRIER;   // all waves' head-h tiles visible; all done computing h-1

    if (h + 1 < NH) {  // issue h+1 into the other buffer BEFORE compute h
      const f16* gq = Qp + (size_t)(bi + q0 * 16 + lr4) * DIM + (h + 1) * DK + kkw * 32 + lc4 * 8;
      const f16* gk = Kp + (size_t)(bj + q0 * 16 + lr4) * DIM + (h + 1) * DK + kkw * 32 + lc4 * 8;
#pragma unroll
      for (int t = 0; t < 2; t++) {
        gload_lds16(gq + (size_t)t * 16 * DIM, &Qs[buf ^ 1][kkw][(q0 + t) * 16 * 32]);
        gload_lds16(gk + (size_t)t * 16 * DIM, &Ks[buf ^ 1][kkw][(q0 + t) * 16 * 32]);
      }
    }

    f16x8 af[2][2], bf[2][2];
#pragma unroll
    for (int mi = 0; mi < 2; mi++)
#pragma unroll
      for (int kk = 0; kk < 2; kk++)
        af[mi][kk] = *(const f16x8*)&Qs[buf][kk][(wm + mi * 16 + l16) * 32 + qd * 8];
#pragma unroll
    for (int ni = 0; ni < 2; ni++)
#pragma unroll
      for (int kk = 0; kk < 2; kk++)
        bf[ni][kk] = *(const f16x8*)&Ks[buf][kk][(wn + ni * 16 + l16) * 32 + qd * 8];
#pragma unroll
    for (int mi = 0; mi < 2; mi++)
#pragma unroll
      for (int ni = 0; ni < 2; ni++) {
        f32x4 s = {0.f, 0.f, 0.f, 0.f};
        s = MFMA(af[mi][0], bf[ni][0], s);  // kk order identical to attn_ctx
        s = MFMA(af[mi][1], bf[ni][1], s);
#pragma unroll
        for (int r = 0; r < 4; r++) dsum[mi][ni][r] += __expf(s[r] * SCALE);
      }
  }
#pragma unroll
  for (int mi = 0; mi < 2; mi++)
#pragma unroll
    for (int ni = 0; ni < 2; ni++)
#pragma unroll
      for (int r = 0; r < 4; r++) {
        const int gi = bi + wm + mi * 16 + qd * 4 + r;
        const int gj = bj + wn + ni * 16 + l16;
        IDn[(size_t)gi * S_LEN + gj] = (f16)(1.f / dsum[mi][ni][r]);
      }
}

// ---------------------------------------------------------------- pass B: ctx
// grid (S/128, NH, 4). i-tile 128 (wave=32 rows), j-range 512 in 16x 32-j
// periods. K/V double-buffered LDS-DMA (16KB); IDn register-prefetched
// (wave-private rows). Pipelined like attn_denom. LDS 26KB -> 6 blocks/CU.
__global__ __launch_bounds__(256, 4) void attn_ctx(const f16* __restrict__ Qp,
                                                   const f16* __restrict__ Kp,
                                                   const f16* __restrict__ Vt,
                                                   const f16* __restrict__ IDn,
                                                   float* __restrict__ Cp) {
  __shared__ __align__(16) f16 Ks[2][2][32 * 32];  // [buf][kk][j][32]
  __shared__ __align__(16) f16 Vs[2][64 * 32];     // [buf][d][j32]
  __shared__ __align__(16) f16 Pl[4][32 * 40];     // stride 40: 2-way conflicts only
  const int tid = threadIdx.x;
  const int wv = tid >> 6;
  const int lane = tid & 63;
  const int qd = lane >> 4;
  const int l16 = lane & 15;
  const int h = blockIdx.y;
  const int i0 = blockIdx.x * 128;
  const int iw = i0 + wv * 32;
  const int jb = blockIdx.z * 512;
  const int lr4 = lane >> 2, lc4 = lane & 3;
  const int kkw = wv & 1;         // K staging: kk slice
  const int rhw = wv >> 1;        // K staging: j-row half
  f16* pl = Pl[wv];

  // persistent Q A-frags
  f16x8 aq[2][2];
#pragma unroll
  for (int mi = 0; mi < 2; mi++)
#pragma unroll
    for (int kk = 0; kk < 2; kk++)
      aq[mi][kk] = *(const f16x8*)(Qp + (size_t)(iw + mi * 16 + l16) * DIM +
                                   h * DK + kk * 32 + qd * 8);

  f32x4 acc[2][4];
#pragma unroll
  for (int a = 0; a < 2; a++)
#pragma unroll
    for (int b = 0; b < 4; b++) acc[a][b] = (f32x4){0.f, 0.f, 0.f, 0.f};

  f16x8 idn[2][2];  // [buf][mi] register-prefetched IDn (A-layout)

  // prologue: stage period 0
  {
    const int j0 = jb;
    gload_lds16(Kp + (size_t)(j0 + rhw * 16 + lr4) * DIM + h * DK + kkw * 32 + lc4 * 8,
                &Ks[0][kkw][(rhw * 16) * 32]);
    gload_lds16(Vt + (size_t)(h * DK + wv * 16 + lr4) * S_LEN + j0 + lc4 * 8,
                &Vs[0][(wv * 16) * 32]);
#pragma unroll
    for (int mi = 0; mi < 2; mi++)
      idn[0][mi] = *(const f16x8*)(IDn + (size_t)(iw + mi * 16 + l16) * S_LEN + j0 + qd * 8);
  }

#pragma unroll
  for (int jt = 0; jt < 16; jt++) {
    const int buf = jt & 1;
    VM_WAIT0;     // own DMA + idn loads for period jt complete
    WG_BARRIER;   // all waves' jt tiles visible; all done computing jt-1

    if (jt + 1 < 16) {  // issue jt+1 BEFORE compute jt -> flight during compute
      const int j1 = jb + (jt + 1) * 32;
      gload_lds16(Kp + (size_t)(j1 + rhw * 16 + lr4) * DIM + h * DK + kkw * 32 + lc4 * 8,
                  &Ks[buf ^ 1][kkw][(rhw * 16) * 32]);
      gload_lds16(Vt + (size_t)(h * DK + wv * 16 + lr4) * S_LEN + j1 + lc4 * 8,
                  &Vs[buf ^ 1][(wv * 16) * 32]);
#pragma unroll
      for (int mi = 0; mi < 2; mi++)
        idn[buf ^ 1][mi] =
            *(const f16x8*)(IDn + (size_t)(iw + mi * 16 + l16) * S_LEN + j1 + qd * 8);
    }

    // ---- QK^T -> exp -> Pl (C-layout, padded)
    f16x8 bk[2][2];
#pragma unroll
    for (int ni = 0; ni < 2; ni++)
#pragma unroll
      for (int kk = 0; kk < 2; kk++)
        bk[ni][kk] = *(const f16x8*)&Ks[buf][kk][(ni * 16 + l16) * 32 + qd * 8];
#pragma unroll
    for (int mi = 0; mi < 2; mi++)
#pragma unroll
      for (int ni = 0; ni < 2; ni++) {
        f32x4 s = {0.f, 0.f, 0.f, 0.f};
        s = MFMA(aq[mi][0], bk[ni][0], s);  // same order as attn_denom
        s = MFMA(aq[mi][1], bk[ni][1], s);
#pragma unroll
        for (int r = 0; r < 4; r++)
          pl[(mi * 16 + qd * 4 + r) * 40 + ni * 16 + l16] = (f16)__expf(s[r] * SCALE);
      }

    // ---- P(A-layout) * IDn, then PV
    f16x8 bv[4];
#pragma unroll
    for (int nd = 0; nd < 4; nd++)
      bv[nd] = *(const f16x8*)&Vs[buf][(nd * 16 + l16) * 32 + qd * 8];
#pragma unroll
    for (int mi = 0; mi < 2; mi++) {
      f16x8 ef = *(const f16x8*)&pl[(mi * 16 + l16) * 40 + qd * 8];  // wave-private
      f16x8 p = ef * idn[buf][mi];
#pragma unroll
      for (int nd = 0; nd < 4; nd++)
        acc[mi][nd] = MFMA(p, bv[nd], acc[mi][nd]);
    }
  }

#pragma unroll
  for (int mi = 0; mi < 2; mi++)
#pragma unroll
    for (int nd = 0; nd < 4; nd++)
#pragma unroll
      for (int r = 0; r < 4; r++)
        atomicAdd(&Cp[(size_t)(iw + mi * 16 + qd * 4 + r) * DIM + h * DK + nd * 16 + l16],
                  acc[mi][nd][r]);
}

// ---------------------------------------------------------------- launcher
extern "C" void kernel_launch(void* const* d_in, const int* in_sizes, int n_in,
                              void* d_out, int out_size, void* d_ws, size_t ws_size,
                              hipStream_t stream) {
  const float* q  = (const float*)d_in[0];
  const float* k  = (const float*)d_in[1];
  const float* v  = (const float*)d_in[2];
  const float* Wq = (const float*)d_in[3];
  const float* bq = (const float*)d_in[4];
  const float* Wk = (const float*)d_in[5];
  const float* bk = (const float*)d_in[6];
  const float* Wv = (const float*)d_in[7];
  const float* bv = (const float*)d_in[8];
  const float* Wo = (const float*)d_in[9];
  const float* bo = (const float*)d_in[10];
  float* out = (float*)d_out;

  // ws layout (32 MB). Aliases (stream-ordered): IDn over qh+kh [dead after
  // gemm_qkv]; Cp (fp32) over vh+wqh+wkh [dead after gemm_qkv]; Ct over qh
  // [IDn dead after attn_ctx]. woh NOT aliased.
  f16* w = (f16*)d_ws;
  f16* qh  = w;                          // 0..4MB
  f16* kh  = qh + (size_t)S_LEN * DIM;   // 4..8
  f16* vh  = kh + (size_t)S_LEN * DIM;   // 8..12
  f16* wqh = vh + (size_t)S_LEN * DIM;   // 12..14
  f16* wkh = wqh + (size_t)DIM * DIM;    // 14..16
  f16* wvh = wkh + (size_t)DIM * DIM;    // 16..18
  f16* woh = wvh + (size_t)DIM * DIM;    // 18..20
  f16* Qp  = woh + (size_t)DIM * DIM;    // 20..24
  f16* Kp  = Qp + (size_t)S_LEN * DIM;   // 24..28
  f16* Vt  = Kp + (size_t)S_LEN * DIM;   // 28..32
  f16* IDn = qh;                         // 0..8MB
  float* Cp = (float*)vh;                // 8..16MB
  f16* Ct  = qh;                         // 0..4MB

  dim3 b256(256);
  cvt_all<<<dim3(1024, 10), b256, 0, stream>>>(q, k, v, Wq, Wk, Wv, Wo,
                                               qh, kh, vh, wqh, wkh, wvh, woh);

  gemm_qkv<<<dim3(DIM / 64, S_LEN / 128, 3), b256, 0, stream>>>(
      qh, kh, vh, wqh, wkh, wvh, bq, bk, bv, Qp, Kp, Vt);

  hipMemsetAsync(Cp, 0, (size_t)S_LEN * DIM * sizeof(float), stream);
  hipMemsetAsync(out, 0, (size_t)S_LEN * DIM * sizeof(float), stream);

  attn_denom<<<dim3(S_LEN / 64, S_LEN / 64), b256, 0, stream>>>(Qp, Kp, IDn);
  attn_ctx<<<dim3(S_LEN / 128, NH, 4), b256, 0, stream>>>(Qp, Kp, Vt, IDn, Cp);

  const int nqkv4 = S_LEN * DIM / 4;
  cvt_f32_f16<<<nqkv4 / 256, b256, 0, stream>>>(Cp, Ct, nqkv4);

  gemm_out<<<dim3(DIM / 64, S_LEN / 128, 2), b256, 0, stream>>>(Ct, woh, bo, out);
}

// Round 7
// 228.147 us; speedup vs baseline: 1.1328x; 1.1328x over previous
//
#include <hip/hip_runtime.h>
#include <hip/hip_fp16.h>

// MHA with softmax over HEADS axis. R7: fix denom register blowup (unroll 2,
// not full), pipeline both GEMMs (BK-32 double-buffered, raw s_barrier +
// vmcnt(0), prefetch-before-compute), exp via v_exp_f32 with folded constant.

typedef _Float16 f16;
typedef _Float16 f16x4 __attribute__((ext_vector_type(4)));
typedef _Float16 f16x8 __attribute__((ext_vector_type(8)));
typedef float    f32x4 __attribute__((ext_vector_type(4)));

#define S_LEN 2048
#define DIM   1024
#define NH    16
#define DK    64
// exp(s * 0.125) = exp2(s * log2(e)/8)
#define EXP2K 0.1803368801111244f

#define MFMA(a, b, c) __builtin_amdgcn_mfma_f32_16x16x32_f16(a, b, c, 0, 0, 0)

#define VM_WAIT0   asm volatile("s_waitcnt vmcnt(0)" ::: "memory")
#define WG_BARRIER asm volatile("s_barrier" ::: "memory")

typedef __attribute__((address_space(1))) void g_void;
typedef __attribute__((address_space(3))) void l_void;

static __device__ __forceinline__ void gload_lds16(const void* g, void* l) {
  __builtin_amdgcn_global_load_lds((g_void*)g, (l_void*)l, 16, 0, 0);
}

static __device__ __forceinline__ float exp_s(float s) {
  return __builtin_amdgcn_exp2f(s * EXP2K);  // identical in denom & ctx
}

// ---------------------------------------------------------------- merged cvt fp32->f16
__global__ __launch_bounds__(256) void cvt_all(
    const float* __restrict__ q, const float* __restrict__ k, const float* __restrict__ v,
    const float* __restrict__ Wq, const float* __restrict__ Wk, const float* __restrict__ Wv,
    const float* __restrict__ Wo, f16* __restrict__ qh, f16* __restrict__ kh,
    f16* __restrict__ vh, f16* __restrict__ wqh, f16* __restrict__ wkh,
    f16* __restrict__ wvh, f16* __restrict__ woh) {
  const size_t M = 1048576;
  const int seg = blockIdx.y;
  const float* src;
  f16* dst;
  switch (seg) {
    case 0: src = q;      dst = qh;      break;
    case 1: src = q + M;  dst = qh + M;  break;
    case 2: src = k;      dst = kh;      break;
    case 3: src = k + M;  dst = kh + M;  break;
    case 4: src = v;      dst = vh;      break;
    case 5: src = v + M;  dst = vh + M;  break;
    case 6: src = Wq;     dst = wqh;     break;
    case 7: src = Wk;     dst = wkh;     break;
    case 8: src = Wv;     dst = wvh;     break;
    default: src = Wo;    dst = woh;     break;
  }
  int i = blockIdx.x * 256 + threadIdx.x;
  float4 vv = ((const float4*)src)[i];
  f16x4 o = {(f16)vv.x, (f16)vv.y, (f16)vv.z, (f16)vv.w};
  ((f16x4*)dst)[i] = o;
}

__global__ __launch_bounds__(256) void cvt_f32_f16(const float* __restrict__ src,
                                                   f16* __restrict__ dst, int n4) {
  int i = blockIdx.x * 256 + threadIdx.x;
  if (i < n4) {
    float4 v = ((const float4*)src)[i];
    f16x4 o = {(f16)v.x, (f16)v.y, (f16)v.z, (f16)v.w};
    ((f16x4*)dst)[i] = o;
  }
}

// ---------------------------------------------------------------- pipelined 128x64 GEMM core
// BK=32 double-buffered. As:[2][128*32] Bs:[2][64*32] (24KB). 3 DMA/wave +
// 8 MFMA/wave per period; next period's DMA issued before compute.
static __device__ __forceinline__ void gemm32_core(const f16* __restrict__ X,
                                                   const f16* __restrict__ W,
                                                   int k0, int k1, int bm, int bn,
                                                   f16* As, f16* Bs,
                                                   f32x4 (&acc)[4][2]) {
  const int tid = threadIdx.x;
  const int wv = tid >> 6;
  const int lane = tid & 63;
  const int qd = lane >> 4;
  const int l16 = lane & 15;
  const int wm = (wv & 1) * 64;
  const int wn = (wv >> 1) * 32;
  const int lr4 = lane >> 2, lc4 = lane & 3;

  const f16* gA = X + (size_t)(bm + wv * 32 + lr4) * DIM + k0 + lc4 * 8;
  const f16* gB = W + (size_t)(bn + wv * 16 + lr4) * DIM + k0 + lc4 * 8;
  const int np = (k1 - k0) >> 5;

  // prologue: period 0 into buf 0
  gload_lds16(gA, As + (wv * 32) * 32);
  gload_lds16(gA + 16 * DIM, As + (wv * 32 + 16) * 32);
  gload_lds16(gB, Bs + (wv * 16) * 32);

#pragma unroll 2
  for (int t = 0; t < np; t++) {
    const int buf = t & 1;
    VM_WAIT0;
    WG_BARRIER;
    if (t + 1 < np) {
      const f16* gA1 = gA + (t + 1) * 32;
      const f16* gB1 = gB + (t + 1) * 32;
      f16* dA = As + (buf ^ 1) * (128 * 32);
      f16* dB = Bs + (buf ^ 1) * (64 * 32);
      gload_lds16(gA1, dA + (wv * 32) * 32);
      gload_lds16(gA1 + 16 * DIM, dA + (wv * 32 + 16) * 32);
      gload_lds16(gB1, dB + (wv * 16) * 32);
    }
    const f16* A = As + buf * (128 * 32);
    const f16* B = Bs + buf * (64 * 32);
    f16x8 bf[2];
#pragma unroll
    for (int ni = 0; ni < 2; ni++)
      bf[ni] = *(const f16x8*)&B[(wn + ni * 16 + l16) * 32 + qd * 8];
#pragma unroll
    for (int mi = 0; mi < 4; mi++) {
      f16x8 af = *(const f16x8*)&A[(wm + mi * 16 + l16) * 32 + qd * 8];
#pragma unroll
      for (int ni = 0; ni < 2; ni++)
        acc[mi][ni] = MFMA(af, bf[ni], acc[mi][ni]);
    }
  }
}

// ---------------------------------------------------------------- merged QKV proj
__global__ __launch_bounds__(256) void gemm_qkv(
    const f16* __restrict__ X0, const f16* __restrict__ X1, const f16* __restrict__ X2,
    const f16* __restrict__ W0, const f16* __restrict__ W1, const f16* __restrict__ W2,
    const float* __restrict__ b0, const float* __restrict__ b1, const float* __restrict__ b2,
    f16* __restrict__ o0, f16* __restrict__ o1, f16* __restrict__ o2) {
  __shared__ __align__(16) f16 As[2 * 128 * 32];
  __shared__ __align__(16) f16 Bs[2 * 64 * 32];
  const int z = blockIdx.z;
  const f16* X = z == 0 ? X0 : z == 1 ? X1 : X2;
  const f16* W = z == 0 ? W0 : z == 1 ? W1 : W2;
  const float* bias = z == 0 ? b0 : z == 1 ? b1 : b2;
  f16* outh = z == 0 ? o0 : z == 1 ? o1 : o2;

  const int bm = blockIdx.y * 128, bn = blockIdx.x * 64;
  f32x4 acc[4][2];
#pragma unroll
  for (int a = 0; a < 4; a++)
#pragma unroll
    for (int b = 0; b < 2; b++) acc[a][b] = (f32x4){0.f, 0.f, 0.f, 0.f};

  gemm32_core(X, W, 0, DIM, bm, bn, As, Bs, acc);

  const int tid = threadIdx.x;
  const int wv = tid >> 6, lane = tid & 63;
  const int qd = lane >> 4, l16 = lane & 15;
  const int wm = (wv & 1) * 64, wn = (wv >> 1) * 32;
#pragma unroll
  for (int mi = 0; mi < 4; mi++) {
#pragma unroll
    for (int ni = 0; ni < 2; ni++) {
      const int gm = bm + wm + mi * 16 + qd * 4;
      const int gn = bn + wn + ni * 16 + l16;
      const float bs = bias[gn];
      if (z == 2) {
        f16x4 o = {(f16)(acc[mi][ni][0] + bs), (f16)(acc[mi][ni][1] + bs),
                   (f16)(acc[mi][ni][2] + bs), (f16)(acc[mi][ni][3] + bs)};
        *(f16x4*)&outh[(size_t)gn * S_LEN + gm] = o;  // Vt[d][j]
      } else {
#pragma unroll
        for (int r = 0; r < 4; r++)
          outh[(size_t)(gm + r) * DIM + gn] = (f16)(acc[mi][ni][r] + bs);
      }
    }
  }
}

// ---------------------------------------------------------------- out GEMM 128x64, splitK2
__global__ __launch_bounds__(256) void gemm_out(const f16* __restrict__ X,
                                                const f16* __restrict__ W,
                                                const float* __restrict__ bias,
                                                float* __restrict__ outf) {
  __shared__ __align__(16) f16 As[2 * 128 * 32];
  __shared__ __align__(16) f16 Bs[2 * 64 * 32];
  const int z = blockIdx.z;
  const int bm = blockIdx.y * 128, bn = blockIdx.x * 64;
  f32x4 acc[4][2];
#pragma unroll
  for (int a = 0; a < 4; a++)
#pragma unroll
    for (int b = 0; b < 2; b++) acc[a][b] = (f32x4){0.f, 0.f, 0.f, 0.f};

  gemm32_core(X, W, z * (DIM / 2), (z + 1) * (DIM / 2), bm, bn, As, Bs, acc);

  const int tid = threadIdx.x;
  const int wv = tid >> 6, lane = tid & 63;
  const int qd = lane >> 4, l16 = lane & 15;
  const int wm = (wv & 1) * 64, wn = (wv >> 1) * 32;
#pragma unroll
  for (int mi = 0; mi < 4; mi++) {
#pragma unroll
    for (int ni = 0; ni < 2; ni++) {
      const int gm = bm + wm + mi * 16 + qd * 4;
      const int gn = bn + wn + ni * 16 + l16;
      const float bs = z == 0 ? bias[gn] : 0.f;
#pragma unroll
      for (int r = 0; r < 4; r++)
        atomicAdd(&outf[(size_t)(gm + r) * DIM + gn], acc[mi][ni][r] + bs);
    }
  }
}

// ---------------------------------------------------------------- pass A: IDn = 1/sum_h exp
// 64x64 tile, grid 1024. Pipelined per-head double-buffer; unroll 2 ONLY
// (R6's full unroll -> 156 VGPR -> 10% occupancy).
__global__ __launch_bounds__(256) void attn_denom(const f16* __restrict__ Qp,
                                                  const f16* __restrict__ Kp,
                                                  f16* __restrict__ IDn) {
  __shared__ __align__(16) f16 Qs[2][2][64 * 32];  // [buf][kk][row][32]
  __shared__ __align__(16) f16 Ks[2][2][64 * 32];
  const int tid = threadIdx.x;
  const int wv = tid >> 6;
  const int lane = tid & 63;
  const int qd = lane >> 4;
  const int l16 = lane & 15;
  const int wm = (wv & 1) * 32, wn = (wv >> 1) * 32;
  const int bi = blockIdx.y * 64, bj = blockIdx.x * 64;
  const int lr4 = lane >> 2, lc4 = lane & 3;
  const int kkw = wv & 1;
  const int q0 = (wv >> 1) * 2;

  f32x4 dsum[2][2];
#pragma unroll
  for (int a = 0; a < 2; a++)
#pragma unroll
    for (int b = 0; b < 2; b++) dsum[a][b] = (f32x4){0.f, 0.f, 0.f, 0.f};

  // prologue: head 0 -> buf 0
  {
    const f16* gq = Qp + (size_t)(bi + q0 * 16 + lr4) * DIM + kkw * 32 + lc4 * 8;
    const f16* gk = Kp + (size_t)(bj + q0 * 16 + lr4) * DIM + kkw * 32 + lc4 * 8;
#pragma unroll
    for (int t = 0; t < 2; t++) {
      gload_lds16(gq + (size_t)t * 16 * DIM, &Qs[0][kkw][(q0 + t) * 16 * 32]);
      gload_lds16(gk + (size_t)t * 16 * DIM, &Ks[0][kkw][(q0 + t) * 16 * 32]);
    }
  }

#pragma unroll 2
  for (int h = 0; h < NH; h++) {
    const int buf = h & 1;
    VM_WAIT0;
    WG_BARRIER;
    if (h + 1 < NH) {
      const f16* gq = Qp + (size_t)(bi + q0 * 16 + lr4) * DIM + (h + 1) * DK + kkw * 32 + lc4 * 8;
      const f16* gk = Kp + (size_t)(bj + q0 * 16 + lr4) * DIM + (h + 1) * DK + kkw * 32 + lc4 * 8;
#pragma unroll
      for (int t = 0; t < 2; t++) {
        gload_lds16(gq + (size_t)t * 16 * DIM, &Qs[buf ^ 1][kkw][(q0 + t) * 16 * 32]);
        gload_lds16(gk + (size_t)t * 16 * DIM, &Ks[buf ^ 1][kkw][(q0 + t) * 16 * 32]);
      }
    }

#pragma unroll
    for (int mi = 0; mi < 2; mi++) {
      f16x8 af0 = *(const f16x8*)&Qs[buf][0][(wm + mi * 16 + l16) * 32 + qd * 8];
      f16x8 af1 = *(const f16x8*)&Qs[buf][1][(wm + mi * 16 + l16) * 32 + qd * 8];
#pragma unroll
      for (int ni = 0; ni < 2; ni++) {
        f16x8 bf0 = *(const f16x8*)&Ks[buf][0][(wn + ni * 16 + l16) * 32 + qd * 8];
        f16x8 bf1 = *(const f16x8*)&Ks[buf][1][(wn + ni * 16 + l16) * 32 + qd * 8];
        f32x4 s = {0.f, 0.f, 0.f, 0.f};
        s = MFMA(af0, bf0, s);  // kk order identical to attn_ctx
        s = MFMA(af1, bf1, s);
#pragma unroll
        for (int r = 0; r < 4; r++) dsum[mi][ni][r] += exp_s(s[r]);
      }
    }
  }
#pragma unroll
  for (int mi = 0; mi < 2; mi++)
#pragma unroll
    for (int ni = 0; ni < 2; ni++)
#pragma unroll
      for (int r = 0; r < 4; r++) {
        const int gi = bi + wm + mi * 16 + qd * 4 + r;
        const int gj = bj + wn + ni * 16 + l16;
        IDn[(size_t)gi * S_LEN + gj] = (f16)(1.f / dsum[mi][ni][r]);
      }
}

// ---------------------------------------------------------------- pass B: ctx
// grid (S/128, NH, 4). Pipelined K/V LDS double-buffer + register IDn prefetch.
__global__ __launch_bounds__(256, 4) void attn_ctx(const f16* __restrict__ Qp,
                                                   const f16* __restrict__ Kp,
                                                   const f16* __restrict__ Vt,
                                                   const f16* __restrict__ IDn,
                                                   float* __restrict__ Cp) {
  __shared__ __align__(16) f16 Ks[2][2][32 * 32];  // [buf][kk][j][32]
  __shared__ __align__(16) f16 Vs[2][64 * 32];     // [buf][d][j32]
  __shared__ __align__(16) f16 Pl[4][32 * 40];     // stride 40: 2-way only
  const int tid = threadIdx.x;
  const int wv = tid >> 6;
  const int lane = tid & 63;
  const int qd = lane >> 4;
  const int l16 = lane & 15;
  const int h = blockIdx.y;
  const int i0 = blockIdx.x * 128;
  const int iw = i0 + wv * 32;
  const int jb = blockIdx.z * 512;
  const int lr4 = lane >> 2, lc4 = lane & 3;
  const int kkw = wv & 1;
  const int rhw = wv >> 1;
  f16* pl = Pl[wv];

  f16x8 aq[2][2];
#pragma unroll
  for (int mi = 0; mi < 2; mi++)
#pragma unroll
    for (int kk = 0; kk < 2; kk++)
      aq[mi][kk] = *(const f16x8*)(Qp + (size_t)(iw + mi * 16 + l16) * DIM +
                                   h * DK + kk * 32 + qd * 8);

  f32x4 acc[2][4];
#pragma unroll
  for (int a = 0; a < 2; a++)
#pragma unroll
    for (int b = 0; b < 4; b++) acc[a][b] = (f32x4){0.f, 0.f, 0.f, 0.f};

  f16x8 idn[2][2];

  {
    const int j0 = jb;
    gload_lds16(Kp + (size_t)(j0 + rhw * 16 + lr4) * DIM + h * DK + kkw * 32 + lc4 * 8,
                &Ks[0][kkw][(rhw * 16) * 32]);
    gload_lds16(Vt + (size_t)(h * DK + wv * 16 + lr4) * S_LEN + j0 + lc4 * 8,
                &Vs[0][(wv * 16) * 32]);
#pragma unroll
    for (int mi = 0; mi < 2; mi++)
      idn[0][mi] = *(const f16x8*)(IDn + (size_t)(iw + mi * 16 + l16) * S_LEN + j0 + qd * 8);
  }

#pragma unroll 2
  for (int jt = 0; jt < 16; jt++) {
    const int buf = jt & 1;
    VM_WAIT0;
    WG_BARRIER;

    if (jt + 1 < 16) {
      const int j1 = jb + (jt + 1) * 32;
      gload_lds16(Kp + (size_t)(j1 + rhw * 16 + lr4) * DIM + h * DK + kkw * 32 + lc4 * 8,
                  &Ks[buf ^ 1][kkw][(rhw * 16) * 32]);
      gload_lds16(Vt + (size_t)(h * DK + wv * 16 + lr4) * S_LEN + j1 + lc4 * 8,
                  &Vs[buf ^ 1][(wv * 16) * 32]);
#pragma unroll
      for (int mi = 0; mi < 2; mi++)
        idn[buf ^ 1][mi] =
            *(const f16x8*)(IDn + (size_t)(iw + mi * 16 + l16) * S_LEN + j1 + qd * 8);
    }

    f16x8 bk[2][2];
#pragma unroll
    for (int ni = 0; ni < 2; ni++)
#pragma unroll
      for (int kk = 0; kk < 2; kk++)
        bk[ni][kk] = *(const f16x8*)&Ks[buf][kk][(ni * 16 + l16) * 32 + qd * 8];
#pragma unroll
    for (int mi = 0; mi < 2; mi++)
#pragma unroll
      for (int ni = 0; ni < 2; ni++) {
        f32x4 s = {0.f, 0.f, 0.f, 0.f};
        s = MFMA(aq[mi][0], bk[ni][0], s);  // same order as attn_denom
        s = MFMA(aq[mi][1], bk[ni][1], s);
#pragma unroll
        for (int r = 0; r < 4; r++)
          pl[(mi * 16 + qd * 4 + r) * 40 + ni * 16 + l16] = (f16)exp_s(s[r]);
      }

    f16x8 bv[4];
#pragma unroll
    for (int nd = 0; nd < 4; nd++)
      bv[nd] = *(const f16x8*)&Vs[buf][(nd * 16 + l16) * 32 + qd * 8];
#pragma unroll
    for (int mi = 0; mi < 2; mi++) {
      f16x8 ef = *(const f16x8*)&pl[(mi * 16 + l16) * 40 + qd * 8];  // wave-private
      f16x8 p = ef * idn[buf][mi];
#pragma unroll
      for (int nd = 0; nd < 4; nd++)
        acc[mi][nd] = MFMA(p, bv[nd], acc[mi][nd]);
    }
  }

#pragma unroll
  for (int mi = 0; mi < 2; mi++)
#pragma unroll
    for (int nd = 0; nd < 4; nd++)
#pragma unroll
      for (int r = 0; r < 4; r++)
        atomicAdd(&Cp[(size_t)(iw + mi * 16 + qd * 4 + r) * DIM + h * DK + nd * 16 + l16],
                  acc[mi][nd][r]);
}

// ---------------------------------------------------------------- launcher
extern "C" void kernel_launch(void* const* d_in, const int* in_sizes, int n_in,
                              void* d_out, int out_size, void* d_ws, size_t ws_size,
                              hipStream_t stream) {
  const float* q  = (const float*)d_in[0];
  const float* k  = (const float*)d_in[1];
  const float* v  = (const float*)d_in[2];
  const float* Wq = (const float*)d_in[3];
  const float* bq = (const float*)d_in[4];
  const float* Wk = (const float*)d_in[5];
  const float* bk = (const float*)d_in[6];
  const float* Wv = (const float*)d_in[7];
  const float* bv = (const float*)d_in[8];
  const float* Wo = (const float*)d_in[9];
  const float* bo = (const float*)d_in[10];
  float* out = (float*)d_out;

  f16* w = (f16*)d_ws;
  f16* qh  = w;                          // 0..4MB
  f16* kh  = qh + (size_t)S_LEN * DIM;   // 4..8
  f16* vh  = kh + (size_t)S_LEN * DIM;   // 8..12
  f16* wqh = vh + (size_t)S_LEN * DIM;   // 12..14
  f16* wkh = wqh + (size_t)DIM * DIM;    // 14..16
  f16* wvh = wkh + (size_t)DIM * DIM;    // 16..18
  f16* woh = wvh + (size_t)DIM * DIM;    // 18..20
  f16* Qp  = woh + (size_t)DIM * DIM;    // 20..24
  f16* Kp  = Qp + (size_t)S_LEN * DIM;   // 24..28
  f16* Vt  = Kp + (size_t)S_LEN * DIM;   // 28..32
  f16* IDn = qh;                         // 0..8MB  [qh/kh dead after gemm_qkv]
  float* Cp = (float*)vh;                // 8..16MB [vh/wqh/wkh dead]
  f16* Ct  = qh;                         // 0..4MB  [IDn dead after attn_ctx]

  dim3 b256(256);
  cvt_all<<<dim3(1024, 10), b256, 0, stream>>>(q, k, v, Wq, Wk, Wv, Wo,
                                               qh, kh, vh, wqh, wkh, wvh, woh);

  gemm_qkv<<<dim3(DIM / 64, S_LEN / 128, 3), b256, 0, stream>>>(
      qh, kh, vh, wqh, wkh, wvh, bq, bk, bv, Qp, Kp, Vt);

  hipMemsetAsync(Cp, 0, (size_t)S_LEN * DIM * sizeof(float), stream);
  hipMemsetAsync(out, 0, (size_t)S_LEN * DIM * sizeof(float), stream);

  attn_denom<<<dim3(S_LEN / 64, S_LEN / 64), b256, 0, stream>>>(Qp, Kp, IDn);
  attn_ctx<<<dim3(S_LEN / 128, NH, 4), b256, 0, stream>>>(Qp, Kp, Vt, IDn, Cp);

  const int nqkv4 = S_LEN * DIM / 4;
  cvt_f32_f16<<<nqkv4 / 256, b256, 0, stream>>>(Cp, Ct, nqkv4);

  gemm_out<<<dim3(DIM / 64, S_LEN / 128, 2), b256, 0, stream>>>(Ct, woh, bo, out);
}